// Round 1
// baseline (3022.818 us; speedup 1.0000x reference)
//
#include <hip/hip_runtime.h>

#define EPS 1e-5f

// ---------- prep: fold BN0 into W1 (W1p = diag(s0)W1, c1 = t0@W1), BN1 affine (s1,u1) ----------
__global__ void k_prep(const float* __restrict__ W1, const float* __restrict__ b1,
                       const float* __restrict__ g0, const float* __restrict__ be0,
                       const float* __restrict__ m0, const float* __restrict__ v0,
                       const float* __restrict__ g1, const float* __restrict__ be1,
                       const float* __restrict__ m1, const float* __restrict__ v1,
                       float* __restrict__ W1p, float* __restrict__ c1,
                       float* __restrict__ s1, float* __restrict__ u1) {
  int j = threadIdx.x;  // 128 threads, one per output column
  float acc = 0.f;
  for (int k = 0; k < 128; ++k) {
    float s0 = g0[k] * rsqrtf(v0[k] + EPS);
    float t0 = be0[k] - m0[k] * s0;
    float w = W1[k * 128 + j];
    W1p[k * 128 + j] = s0 * w;
    acc = fmaf(t0, w, acc);
  }
  c1[j] = acc;
  float s = g1[j] * rsqrtf(v1[j] + EPS);
  s1[j] = s;
  u1[j] = fmaf(b1[j] - m1[j], s, be1[j]);  // h = relu(agg*s1 + u1)
}

__global__ void k_zero(int* __restrict__ cnt, int n) {
  int i = blockIdx.x * blockDim.x + threadIdx.x;
  if (i < n) cnt[i] = 0;
}

__global__ void k_count(const int* __restrict__ dst, int e, int* __restrict__ cnt) {
  int i = blockIdx.x * blockDim.x + threadIdx.x;
  if (i < e) atomicAdd(&cnt[dst[i]], 1);
}

__global__ void k_dinv(const int* __restrict__ cnt, float* __restrict__ dinv, int n) {
  int i = blockIdx.x * blockDim.x + threadIdx.x;
  if (i < n) dinv[i] = rsqrtf((float)cnt[i] + 1.0f);  // +1 = self-loop; deg>=1 always
}

// ---------- GEMM1: xw1 = x @ W1p + c1   (fp32 vector ALU; 32 rows/block, 4x4 per thread) ----------
__global__ __launch_bounds__(256) void k_gemm1(const float* __restrict__ x,
                                               const float* __restrict__ W1p,
                                               const float* __restrict__ c1,
                                               float* __restrict__ xw1, int n) {
  __shared__ float wlds[64 * 128];   // 32 KB, half of W at a time
  __shared__ float xlds[32 * 132];   // stride 132: 16B-aligned rows + no bank conflict
  const int tid = threadIdx.x;
  const int r0 = blockIdx.x * 32;
  // stage x tile: 32 rows x 128 cols = 1024 float4
  for (int j = 0; j < 4; ++j) {
    int q = tid + 256 * j;
    int row = q >> 5, c4 = q & 31;
    float4 v = make_float4(0.f, 0.f, 0.f, 0.f);
    if (r0 + row < n) v = ((const float4*)x)[(size_t)(r0 + row) * 32 + c4];
    float* p = &xlds[row * 132 + c4 * 4];
    p[0] = v.x; p[1] = v.y; p[2] = v.z; p[3] = v.w;
  }
  const int cg = tid & 31, rg = tid >> 5;
  float4 acc0 = {0,0,0,0}, acc1 = {0,0,0,0}, acc2 = {0,0,0,0}, acc3 = {0,0,0,0};
  for (int kb = 0; kb < 2; ++kb) {
    __syncthreads();
    for (int j = 0; j < 8; ++j) {   // stage W chunk: 64x128 = 2048 float4
      int q = tid + 256 * j;
      ((float4*)wlds)[q] = ((const float4*)W1p)[kb * 2048 + q];
    }
    __syncthreads();
    for (int k = 0; k < 64; k += 4) {
      int kg = kb * 64 + k;
      float4 x0 = *(float4*)&xlds[(rg * 4 + 0) * 132 + kg];
      float4 x1 = *(float4*)&xlds[(rg * 4 + 1) * 132 + kg];
      float4 x2 = *(float4*)&xlds[(rg * 4 + 2) * 132 + kg];
      float4 x3 = *(float4*)&xlds[(rg * 4 + 3) * 132 + kg];
      float4 w0 = *(float4*)&wlds[(k + 0) * 128 + cg * 4];
      float4 w1 = *(float4*)&wlds[(k + 1) * 128 + cg * 4];
      float4 w2 = *(float4*)&wlds[(k + 2) * 128 + cg * 4];
      float4 w3 = *(float4*)&wlds[(k + 3) * 128 + cg * 4];
#define FMA4(A, xs, W) A.x = fmaf(xs, W.x, A.x); A.y = fmaf(xs, W.y, A.y); \
                       A.z = fmaf(xs, W.z, A.z); A.w = fmaf(xs, W.w, A.w)
      FMA4(acc0, x0.x, w0); FMA4(acc0, x0.y, w1); FMA4(acc0, x0.z, w2); FMA4(acc0, x0.w, w3);
      FMA4(acc1, x1.x, w0); FMA4(acc1, x1.y, w1); FMA4(acc1, x1.z, w2); FMA4(acc1, x1.w, w3);
      FMA4(acc2, x2.x, w0); FMA4(acc2, x2.y, w1); FMA4(acc2, x2.z, w2); FMA4(acc2, x2.w, w3);
      FMA4(acc3, x3.x, w0); FMA4(acc3, x3.y, w1); FMA4(acc3, x3.z, w2); FMA4(acc3, x3.w, w3);
#undef FMA4
    }
  }
  float4 cv = *(const float4*)&c1[cg * 4];
  int r = r0 + rg * 4;
  if (r + 0 < n) ((float4*)xw1)[(size_t)(r + 0) * 32 + cg] =
      make_float4(acc0.x + cv.x, acc0.y + cv.y, acc0.z + cv.z, acc0.w + cv.w);
  if (r + 1 < n) ((float4*)xw1)[(size_t)(r + 1) * 32 + cg] =
      make_float4(acc1.x + cv.x, acc1.y + cv.y, acc1.z + cv.z, acc1.w + cv.w);
  if (r + 2 < n) ((float4*)xw1)[(size_t)(r + 2) * 32 + cg] =
      make_float4(acc2.x + cv.x, acc2.y + cv.y, acc2.z + cv.z, acc2.w + cv.w);
  if (r + 3 < n) ((float4*)xw1)[(size_t)(r + 3) * 32 + cg] =
      make_float4(acc3.x + cv.x, acc3.y + cv.y, acc3.z + cv.z, acc3.w + cv.w);
}

// ---------- init agg1 with self-loop contribution ----------
__global__ void k_selfloop1(const float* __restrict__ xw1, const float* __restrict__ dinv,
                            float* __restrict__ agg1, int n) {
  int idx = blockIdx.x * blockDim.x + threadIdx.x;  // float4 index over n*32
  if (idx >= n * 32) return;
  int i = idx >> 5;
  float d = dinv[i];
  float w = d * d;
  float4 v = ((const float4*)xw1)[idx];
  ((float4*)agg1)[idx] = make_float4(v.x * w, v.y * w, v.z * w, v.w * w);
}

// ---------- scatter1: agg1[dst] += xw1[src] * dinv[src]*dinv[dst]  (32 lanes/edge) ----------
__global__ __launch_bounds__(256) void k_scatter1(const int* __restrict__ esrc,
                                                  const int* __restrict__ edst,
                                                  const float* __restrict__ dinv,
                                                  const float* __restrict__ xw1,
                                                  float* __restrict__ agg1, int e) {
  int t = blockIdx.x * 256 + threadIdx.x;
  int eid = t >> 5;
  if (eid >= e) return;
  int c4 = t & 31;
  int s = esrc[eid], d = edst[eid];
  float w = dinv[s] * dinv[d];
  float4 v = ((const float4*)xw1)[(size_t)s * 32 + c4];
  float* o = agg1 + (size_t)d * 128 + c4 * 4;
  atomicAdd(o + 0, v.x * w);
  atomicAdd(o + 1, v.y * w);
  atomicAdd(o + 2, v.z * w);
  atomicAdd(o + 3, v.w * w);
}

// ---------- GEMM2 fused with BN1+ReLU: xw2 = relu(agg1*s1+u1) @ W2  (wave per node) ----------
__global__ __launch_bounds__(256) void k_gemm2(const float* __restrict__ agg1,
                                               const float* __restrict__ s1,
                                               const float* __restrict__ u1,
                                               const float* __restrict__ W2,
                                               float* __restrict__ xw2, int n) {
  int wave = threadIdx.x >> 6;
  int lane = threadIdx.x & 63;
  int i = blockIdx.x * 4 + wave;
  if (i >= n) return;
  float2 a = ((const float2*)agg1)[(size_t)i * 64 + lane];
  float2 sv = ((const float2*)s1)[lane];
  float2 uv = ((const float2*)u1)[lane];
  float h0 = fmaxf(fmaf(a.x, sv.x, uv.x), 0.f);
  float h1 = fmaxf(fmaf(a.y, sv.y, uv.y), 0.f);
  float4 w = ((const float4*)W2)[lane];  // {W2[2l][0],W2[2l][1],W2[2l+1][0],W2[2l+1][1]}
  float p0 = h0 * w.x + h1 * w.z;
  float p1 = h0 * w.y + h1 * w.w;
  for (int off = 32; off > 0; off >>= 1) {
    p0 += __shfl_down(p0, off);
    p1 += __shfl_down(p1, off);
  }
  if (lane == 0) ((float2*)xw2)[i] = make_float2(p0, p1);
}

// ---------- init out with bias + self-loop ----------
__global__ void k_selfloop2(const float* __restrict__ xw2, const float* __restrict__ dinv,
                            const float* __restrict__ b2, float* __restrict__ out, int n) {
  int i = blockIdx.x * blockDim.x + threadIdx.x;
  if (i >= n) return;
  float d = dinv[i];
  float w = d * d;
  float2 v = ((const float2*)xw2)[i];
  ((float2*)out)[i] = make_float2(fmaf(v.x, w, b2[0]), fmaf(v.y, w, b2[1]));
}

// ---------- scatter2: out[dst] += xw2[src] * norm  (thread per edge, 2 channels) ----------
__global__ void k_scatter2(const int* __restrict__ esrc, const int* __restrict__ edst,
                           const float* __restrict__ dinv, const float* __restrict__ xw2,
                           float* __restrict__ out, int e) {
  int eid = blockIdx.x * blockDim.x + threadIdx.x;
  if (eid >= e) return;
  int s = esrc[eid], d = edst[eid];
  float w = dinv[s] * dinv[d];
  float2 v = ((const float2*)xw2)[s];
  atomicAdd(&out[d * 2 + 0], v.x * w);
  atomicAdd(&out[d * 2 + 1], v.y * w);
}

extern "C" void kernel_launch(void* const* d_in, const int* in_sizes, int n_in,
                              void* d_out, int out_size, void* d_ws, size_t ws_size,
                              hipStream_t stream) {
  const float* x   = (const float*)d_in[0];
  const int*   ei  = (const int*)d_in[1];
  const float* g0  = (const float*)d_in[2];
  const float* be0 = (const float*)d_in[3];
  const float* m0  = (const float*)d_in[4];
  const float* v0  = (const float*)d_in[5];
  const float* W1  = (const float*)d_in[6];
  const float* b1  = (const float*)d_in[7];
  const float* g1  = (const float*)d_in[8];
  const float* be1 = (const float*)d_in[9];
  const float* m1  = (const float*)d_in[10];
  const float* v1  = (const float*)d_in[11];
  const float* W2  = (const float*)d_in[12];
  const float* b2  = (const float*)d_in[13];
  float* out = (float*)d_out;

  const int n = in_sizes[0] / 128;
  const int e = in_sizes[1] / 2;
  const int* esrc = ei;
  const int* edst = ei + e;

  // workspace layout (all 16B-aligned given n=50000)
  float* wsf  = (float*)d_ws;
  int*   cnt  = (int*)wsf;                      // n ints
  float* dinv = wsf + n;                        // n
  float* W1p  = dinv + n;                       // 128*128
  float* c1   = W1p + 128 * 128;                // 128
  float* s1   = c1 + 128;                       // 128
  float* u1   = s1 + 128;                       // 128
  float* xw1  = u1 + 128;                       // n*128
  float* agg1 = xw1 + (size_t)n * 128;          // n*128
  float* xw2  = agg1 + (size_t)n * 128;         // n*2

  k_prep<<<1, 128, 0, stream>>>(W1, b1, g0, be0, m0, v0, g1, be1, m1, v1, W1p, c1, s1, u1);
  k_zero<<<(n + 255) / 256, 256, 0, stream>>>(cnt, n);
  k_count<<<(e + 255) / 256, 256, 0, stream>>>(edst, e, cnt);
  k_dinv<<<(n + 255) / 256, 256, 0, stream>>>(cnt, dinv, n);
  k_gemm1<<<(n + 31) / 32, 256, 0, stream>>>(x, W1p, c1, xw1, n);
  k_selfloop1<<<(n * 32 + 255) / 256, 256, 0, stream>>>(xw1, dinv, agg1, n);
  k_scatter1<<<(e * 32 + 255) / 256, 256, 0, stream>>>(esrc, edst, dinv, xw1, agg1, e);
  k_gemm2<<<(n + 3) / 4, 256, 0, stream>>>(agg1, s1, u1, W2, xw2, n);
  k_selfloop2<<<(n + 255) / 256, 256, 0, stream>>>(xw2, dinv, b2, out, n);
  k_scatter2<<<(e + 255) / 256, 256, 0, stream>>>(esrc, edst, dinv, xw2, out, e);
}

// Round 2
// 517.543 us; speedup vs baseline: 5.8407x; 5.8407x over previous
//
#include <hip/hip_runtime.h>

#define EPS 1e-5f

// ---------- prep: fold BN0 into W1 (W1p = diag(s0)W1, c1 = t0@W1), BN1 affine (s1,u1) ----------
__global__ void k_prep(const float* __restrict__ W1, const float* __restrict__ b1,
                       const float* __restrict__ g0, const float* __restrict__ be0,
                       const float* __restrict__ m0, const float* __restrict__ v0,
                       const float* __restrict__ g1, const float* __restrict__ be1,
                       const float* __restrict__ m1, const float* __restrict__ v1,
                       float* __restrict__ W1p, float* __restrict__ c1,
                       float* __restrict__ s1, float* __restrict__ u1) {
  int j = threadIdx.x;  // 128 threads, one per output column
  float acc = 0.f;
  for (int k = 0; k < 128; ++k) {
    float s0 = g0[k] * rsqrtf(v0[k] + EPS);
    float t0 = be0[k] - m0[k] * s0;
    float w = W1[k * 128 + j];
    W1p[k * 128 + j] = s0 * w;
    acc = fmaf(t0, w, acc);
  }
  c1[j] = acc;
  float s = g1[j] * rsqrtf(v1[j] + EPS);
  s1[j] = s;
  u1[j] = fmaf(b1[j] - m1[j], s, be1[j]);  // h = relu(agg*s1 + u1)
}

__global__ void k_zero(int* __restrict__ cnt, int n) {
  int i = blockIdx.x * blockDim.x + threadIdx.x;
  if (i < n) cnt[i] = 0;
}

__global__ void k_count(const int* __restrict__ dst, int e, int* __restrict__ cnt) {
  int i = blockIdx.x * blockDim.x + threadIdx.x;
  if (i < e) atomicAdd(&cnt[dst[i]], 1);
}

__global__ void k_dinv(const int* __restrict__ cnt, float* __restrict__ dinv, int n) {
  int i = blockIdx.x * blockDim.x + threadIdx.x;
  if (i < n) dinv[i] = rsqrtf((float)cnt[i] + 1.0f);  // +1 = self-loop; deg>=1 always
}

// ---------- single-block exclusive scan: cnt[0..n) -> rowptr[0..n], wpos copy ----------
__global__ __launch_bounds__(1024) void k_scan(const int* __restrict__ cnt,
                                               int* __restrict__ rowptr,
                                               int* __restrict__ wpos, int n) {
  __shared__ int wsum[16];
  __shared__ int carry_s;
  if (threadIdx.x == 0) carry_s = 0;
  __syncthreads();
  int nchunks = (n + 1023) / 1024;
  for (int c = 0; c < nchunks; ++c) {
    int i = c * 1024 + threadIdx.x;
    int v = (i < n) ? cnt[i] : 0;
    int lane = threadIdx.x & 63, wid = threadIdx.x >> 6;
    int x = v;  // inclusive scan within wave
    for (int off = 1; off < 64; off <<= 1) {
      int y = __shfl_up(x, off);
      if (lane >= off) x += y;
    }
    if (lane == 63) wsum[wid] = x;
    __syncthreads();
    if (threadIdx.x == 0) {  // serial 16-element exclusive scan of wave totals
      int run = carry_s;
      for (int w = 0; w < 16; ++w) { int t = wsum[w]; wsum[w] = run; run += t; }
      carry_s = run;
    }
    __syncthreads();
    int excl = wsum[wid] + x - v;
    if (i < n) { rowptr[i] = excl; wpos[i] = excl; }
    __syncthreads();  // wsum/carry_s stable before next chunk
  }
  if (threadIdx.x == 0) rowptr[n] = carry_s;
}

// ---------- bucket edges by dst: sorted_src[rowptr[d] ...] = src ----------
__global__ void k_sortedges(const int* __restrict__ esrc, const int* __restrict__ edst,
                            int* __restrict__ wpos, int* __restrict__ sorted_src, int e) {
  int i = blockIdx.x * blockDim.x + threadIdx.x;
  if (i >= e) return;
  int d = edst[i];
  int p = atomicAdd(&wpos[d], 1);
  sorted_src[p] = esrc[i];
}

// ---------- GEMM1: xs = (x @ W1p + c1) * dinv[row]   (fp32 vector ALU) ----------
__global__ __launch_bounds__(256) void k_gemm1(const float* __restrict__ x,
                                               const float* __restrict__ W1p,
                                               const float* __restrict__ c1,
                                               const float* __restrict__ dinv,
                                               float* __restrict__ xs, int n) {
  __shared__ float wlds[64 * 128];   // 32 KB, half of W at a time
  __shared__ float xlds[32 * 132];   // stride 132: 16B-aligned rows + no bank conflict
  const int tid = threadIdx.x;
  const int r0 = blockIdx.x * 32;
  for (int j = 0; j < 4; ++j) {
    int q = tid + 256 * j;
    int row = q >> 5, c4 = q & 31;
    float4 v = make_float4(0.f, 0.f, 0.f, 0.f);
    if (r0 + row < n) v = ((const float4*)x)[(size_t)(r0 + row) * 32 + c4];
    float* p = &xlds[row * 132 + c4 * 4];
    p[0] = v.x; p[1] = v.y; p[2] = v.z; p[3] = v.w;
  }
  const int cg = tid & 31, rg = tid >> 5;
  float4 acc0 = {0,0,0,0}, acc1 = {0,0,0,0}, acc2 = {0,0,0,0}, acc3 = {0,0,0,0};
  for (int kb = 0; kb < 2; ++kb) {
    __syncthreads();
    for (int j = 0; j < 8; ++j) {
      int q = tid + 256 * j;
      ((float4*)wlds)[q] = ((const float4*)W1p)[kb * 2048 + q];
    }
    __syncthreads();
    for (int k = 0; k < 64; k += 4) {
      int kg = kb * 64 + k;
      float4 x0 = *(float4*)&xlds[(rg * 4 + 0) * 132 + kg];
      float4 x1 = *(float4*)&xlds[(rg * 4 + 1) * 132 + kg];
      float4 x2 = *(float4*)&xlds[(rg * 4 + 2) * 132 + kg];
      float4 x3 = *(float4*)&xlds[(rg * 4 + 3) * 132 + kg];
      float4 w0 = *(float4*)&wlds[(k + 0) * 128 + cg * 4];
      float4 w1 = *(float4*)&wlds[(k + 1) * 128 + cg * 4];
      float4 w2 = *(float4*)&wlds[(k + 2) * 128 + cg * 4];
      float4 w3 = *(float4*)&wlds[(k + 3) * 128 + cg * 4];
#define FMA4(A, xsv, W) A.x = fmaf(xsv, W.x, A.x); A.y = fmaf(xsv, W.y, A.y); \
                        A.z = fmaf(xsv, W.z, A.z); A.w = fmaf(xsv, W.w, A.w)
      FMA4(acc0, x0.x, w0); FMA4(acc0, x0.y, w1); FMA4(acc0, x0.z, w2); FMA4(acc0, x0.w, w3);
      FMA4(acc1, x1.x, w0); FMA4(acc1, x1.y, w1); FMA4(acc1, x1.z, w2); FMA4(acc1, x1.w, w3);
      FMA4(acc2, x2.x, w0); FMA4(acc2, x2.y, w1); FMA4(acc2, x2.z, w2); FMA4(acc2, x2.w, w3);
      FMA4(acc3, x3.x, w0); FMA4(acc3, x3.y, w1); FMA4(acc3, x3.z, w2); FMA4(acc3, x3.w, w3);
#undef FMA4
    }
  }
  float4 cv = *(const float4*)&c1[cg * 4];
  int r = r0 + rg * 4;
#define STORE_ROW(A, RR) if (RR < n) { float dd = dinv[RR]; \
    ((float4*)xs)[(size_t)(RR) * 32 + cg] = make_float4((A.x + cv.x) * dd, (A.y + cv.y) * dd, \
                                                        (A.z + cv.z) * dd, (A.w + cv.w) * dd); }
  STORE_ROW(acc0, r + 0); STORE_ROW(acc1, r + 1); STORE_ROW(acc2, r + 2); STORE_ROW(acc3, r + 3);
#undef STORE_ROW
}

// ---------- gather1 fused BN1+ReLU+GEMM2: one wave per dst node ----------
// agg = dinv[d]*(xs[d] + sum xs[src]); h = relu(agg*s1+u1); xs2[d] = (h @ W2) * dinv[d]
__global__ __launch_bounds__(256) void k_gather1(const int* __restrict__ rowptr,
                                                 const int* __restrict__ ssrc,
                                                 const float* __restrict__ xs,
                                                 const float* __restrict__ dinv,
                                                 const float* __restrict__ s1,
                                                 const float* __restrict__ u1,
                                                 const float* __restrict__ W2,
                                                 float* __restrict__ xs2, int n) {
  int wave = threadIdx.x >> 6, lane = threadIdx.x & 63;
  int d = blockIdx.x * 4 + wave;
  if (d >= n) return;
  const float2* xsv = (const float2*)xs;
  float2 acc = xsv[(size_t)d * 64 + lane];  // self-loop term
  int beg = rowptr[d], end = rowptr[d + 1];
  int k = beg;
  for (; k + 1 < end; k += 2) {  // unroll x2: two row-loads in flight
    int s0 = ssrc[k], s1i = ssrc[k + 1];
    float2 v0 = xsv[(size_t)s0 * 64 + lane];
    float2 v1 = xsv[(size_t)s1i * 64 + lane];
    acc.x += v0.x + v1.x; acc.y += v0.y + v1.y;
  }
  if (k < end) {
    float2 v = xsv[(size_t)ssrc[k] * 64 + lane];
    acc.x += v.x; acc.y += v.y;
  }
  float dd = dinv[d];
  float2 sv = ((const float2*)s1)[lane];
  float2 uv = ((const float2*)u1)[lane];
  float h0 = fmaxf(fmaf(acc.x * dd, sv.x, uv.x), 0.f);
  float h1 = fmaxf(fmaf(acc.y * dd, sv.y, uv.y), 0.f);
  float4 w = ((const float4*)W2)[lane];  // {W2[2l][0],W2[2l][1],W2[2l+1][0],W2[2l+1][1]}
  float p0 = fmaf(h0, w.x, h1 * w.z);
  float p1 = fmaf(h0, w.y, h1 * w.w);
  for (int off = 32; off > 0; off >>= 1) {
    p0 += __shfl_down(p0, off);
    p1 += __shfl_down(p1, off);
  }
  if (lane == 0) ((float2*)xs2)[d] = make_float2(p0 * dd, p1 * dd);
}

// ---------- gather2: out[d] = b2 + dinv[d]*(xs2[d] + sum xs2[src]) ----------
__global__ __launch_bounds__(256) void k_gather2(const int* __restrict__ rowptr,
                                                 const int* __restrict__ ssrc,
                                                 const float* __restrict__ xs2,
                                                 const float* __restrict__ dinv,
                                                 const float* __restrict__ b2,
                                                 float* __restrict__ out, int n) {
  int wave = threadIdx.x >> 6, lane = threadIdx.x & 63;
  int d = blockIdx.x * 4 + wave;
  if (d >= n) return;
  int beg = rowptr[d], end = rowptr[d + 1];
  float p0 = 0.f, p1 = 0.f;
  for (int k = beg + lane; k < end; k += 64) {
    int s = ssrc[k];
    float2 v = ((const float2*)xs2)[s];
    p0 += v.x; p1 += v.y;
  }
  for (int off = 32; off > 0; off >>= 1) {
    p0 += __shfl_down(p0, off);
    p1 += __shfl_down(p1, off);
  }
  if (lane == 0) {
    float dd = dinv[d];
    float2 self = ((const float2*)xs2)[d];
    out[d * 2 + 0] = fmaf(dd, p0 + self.x, b2[0]);
    out[d * 2 + 1] = fmaf(dd, p1 + self.y, b2[1]);
  }
}

extern "C" void kernel_launch(void* const* d_in, const int* in_sizes, int n_in,
                              void* d_out, int out_size, void* d_ws, size_t ws_size,
                              hipStream_t stream) {
  const float* x   = (const float*)d_in[0];
  const int*   ei  = (const int*)d_in[1];
  const float* g0  = (const float*)d_in[2];
  const float* be0 = (const float*)d_in[3];
  const float* m0  = (const float*)d_in[4];
  const float* v0  = (const float*)d_in[5];
  const float* W1  = (const float*)d_in[6];
  const float* b1  = (const float*)d_in[7];
  const float* g1  = (const float*)d_in[8];
  const float* be1 = (const float*)d_in[9];
  const float* m1  = (const float*)d_in[10];
  const float* v1  = (const float*)d_in[11];
  const float* W2  = (const float*)d_in[12];
  const float* b2  = (const float*)d_in[13];
  float* out = (float*)d_out;

  const int n = in_sizes[0] / 128;
  const int e = in_sizes[1] / 2;
  const int* esrc = ei;
  const int* edst = ei + e;

  // workspace layout (all 16B-aligned; n=50000 divisible by 4)
  int*   wsi        = (int*)d_ws;
  int*   cnt        = wsi;                       // n
  int*   rowptr     = cnt + n;                   // n+1 (pad to n+4)
  int*   wpos       = rowptr + n + 4;            // n
  int*   sorted_src = wpos + n;                  // e
  float* wsf        = (float*)(sorted_src + e);
  float* dinv       = wsf;                       // n
  float* W1p        = dinv + n;                  // 128*128
  float* c1         = W1p + 128 * 128;           // 128
  float* s1         = c1 + 128;                  // 128
  float* u1         = s1 + 128;                  // 128
  float* xs         = u1 + 128;                  // n*128
  float* xs2        = xs + (size_t)n * 128;      // n*2

  k_prep<<<1, 128, 0, stream>>>(W1, b1, g0, be0, m0, v0, g1, be1, m1, v1, W1p, c1, s1, u1);
  k_zero<<<(n + 255) / 256, 256, 0, stream>>>(cnt, n);
  k_count<<<(e + 255) / 256, 256, 0, stream>>>(edst, e, cnt);
  k_dinv<<<(n + 255) / 256, 256, 0, stream>>>(cnt, dinv, n);
  k_scan<<<1, 1024, 0, stream>>>(cnt, rowptr, wpos, n);
  k_sortedges<<<(e + 255) / 256, 256, 0, stream>>>(esrc, edst, wpos, sorted_src, e);
  k_gemm1<<<(n + 31) / 32, 256, 0, stream>>>(x, W1p, c1, dinv, xs, n);
  k_gather1<<<(n + 3) / 4, 256, 0, stream>>>(rowptr, sorted_src, xs, dinv, s1, u1, W2, xs2, n);
  k_gather2<<<(n + 3) / 4, 256, 0, stream>>>(rowptr, sorted_src, xs2, dinv, b2, out, n);
}